// Round 6
// baseline (872.268 us; speedup 1.0000x reference)
//
#include <hip/hip_runtime.h>
#include <math.h>

// ---------------------------------------------------------------------------
// CrossModal_NN — round 6: pipelined bilinear (dbuf sA + deferred reduce,
// 1 barrier/m-step) + dispatch fusion (36 -> 18 launches):
//   conv_multi (6 weight converts), pack_mmfa (8 mmfa W + biases),
//   z-fused GEMM pairs (ms, qkv, sigm, out1, out2), fused classifier.
// ---------------------------------------------------------------------------

typedef short short8   __attribute__((ext_vector_type(8)));
typedef float floatx4  __attribute__((ext_vector_type(4)));

constexpr float NORM = 0.0625f; // 1/sqrt(256), applied AFTER softmax (faithful)

__device__ __forceinline__ unsigned short f2bf(float f) {
    union { float f; unsigned int u; } v; v.f = f;
    unsigned int r = v.u + 0x7fffu + ((v.u >> 16) & 1u); // RNE
    return (unsigned short)(r >> 16);
}
__device__ __forceinline__ float bf2f(unsigned short s) {
    union { unsigned int u; float f; } v; v.u = ((unsigned int)s) << 16;
    return v.f;
}

// ---------------- bf16 MFMA GEMM (z-fused pair): C = act(A @ W^T + bias) ----
template<int ACT>
__global__ __launch_bounds__(256)
void gemm_mfma_z(const float* __restrict__ A0, const float* __restrict__ A1,
                 const unsigned short* __restrict__ Wp0,
                 const unsigned short* __restrict__ Wp1,
                 const float* __restrict__ b0, const float* __restrict__ b1,
                 float* __restrict__ C0, float* __restrict__ C1,
                 int M, int N, int K)
{
    const float* A = blockIdx.z ? A1 : A0;
    const unsigned short* W = blockIdx.z ? Wp1 : Wp0;
    const float* bias = blockIdx.z ? b1 : b0;
    float* C = blockIdx.z ? C1 : C0;

    __shared__ short sA[64][72];
    __shared__ short sW[64][72];
    const int tid  = threadIdx.x;
    const int wave = tid >> 6, lane = tid & 63;
    const int quad = lane >> 4, l15 = lane & 15;
    const int m0 = blockIdx.y * 64, n0 = blockIdx.x * 64;
    const int mw = (wave & 1) * 32, nw = (wave >> 1) * 32;
    const int srow = tid >> 2, sseg = tid & 3;

    floatx4 P[2][2];
    #pragma unroll
    for (int f = 0; f < 2; f++)
        #pragma unroll
        for (int g = 0; g < 2; g++)
            P[f][g] = (floatx4){0.f, 0.f, 0.f, 0.f};

    for (int k0 = 0; k0 < K; k0 += 64) {
        const float* ap = A + (size_t)(m0 + srow) * K + k0 + sseg * 16;
        float4 a0 = *(const float4*)(ap);
        float4 a1 = *(const float4*)(ap + 4);
        float4 a2 = *(const float4*)(ap + 8);
        float4 a3 = *(const float4*)(ap + 12);
        union { unsigned short s[8]; short8 v; } p0, p1;
        p0.s[0] = f2bf(a0.x); p0.s[1] = f2bf(a0.y); p0.s[2] = f2bf(a0.z); p0.s[3] = f2bf(a0.w);
        p0.s[4] = f2bf(a1.x); p0.s[5] = f2bf(a1.y); p0.s[6] = f2bf(a1.z); p0.s[7] = f2bf(a1.w);
        p1.s[0] = f2bf(a2.x); p1.s[1] = f2bf(a2.y); p1.s[2] = f2bf(a2.z); p1.s[3] = f2bf(a2.w);
        p1.s[4] = f2bf(a3.x); p1.s[5] = f2bf(a3.y); p1.s[6] = f2bf(a3.z); p1.s[7] = f2bf(a3.w);
        *(short8*)&sA[srow][sseg * 16]     = p0.v;
        *(short8*)&sA[srow][sseg * 16 + 8] = p1.v;
        const unsigned short* wp = W + (size_t)(n0 + srow) * K + k0 + sseg * 16;
        *(short8*)&sW[srow][sseg * 16]     = *(const short8*)wp;
        *(short8*)&sW[srow][sseg * 16 + 8] = *(const short8*)(wp + 8);
        __syncthreads();
        #pragma unroll
        for (int kh = 0; kh < 2; kh++) {
            short8 af[2], wf[2];
            af[0] = *(short8*)&sA[mw + l15][kh * 32 + quad * 8];
            af[1] = *(short8*)&sA[mw + 16 + l15][kh * 32 + quad * 8];
            wf[0] = *(short8*)&sW[nw + l15][kh * 32 + quad * 8];
            wf[1] = *(short8*)&sW[nw + 16 + l15][kh * 32 + quad * 8];
            #pragma unroll
            for (int f = 0; f < 2; f++)
                #pragma unroll
                for (int g = 0; g < 2; g++)
                    P[f][g] = __builtin_amdgcn_mfma_f32_16x16x32_bf16(af[f], wf[g], P[f][g], 0, 0, 0);
        }
        __syncthreads();
    }
    #pragma unroll
    for (int f = 0; f < 2; f++)
        #pragma unroll
        for (int g = 0; g < 2; g++)
            #pragma unroll
            for (int r = 0; r < 4; r++) {
                int m = m0 + mw + 16 * f + quad * 4 + r;
                int n = n0 + nw + 16 * g + l15;
                float v = P[f][g][r] + bias[n];
                if (ACT) v = fmaxf(v, 0.f);
                C[(size_t)m * N + n] = v;
            }
}

// ---- z-fused GEMM with sigmoid(G*alpha)->bf16 epilogue ---------------------
__global__ __launch_bounds__(256)
void gemm_sigm_z(const float* __restrict__ A0, const float* __restrict__ A1,
                 const unsigned short* __restrict__ Wp0,
                 const unsigned short* __restrict__ Wp1,
                 const float* __restrict__ b0, const float* __restrict__ b1,
                 unsigned short* __restrict__ O0, unsigned short* __restrict__ O1,
                 int M, int N, int K)
{
    const float* A = blockIdx.z ? A1 : A0;           // alpha lives in A[.,256:512]
    const unsigned short* W = blockIdx.z ? Wp1 : Wp0;
    const float* bias = blockIdx.z ? b1 : b0;
    unsigned short* Cbf = blockIdx.z ? O1 : O0;

    __shared__ short sA[64][72];
    __shared__ short sW[64][72];
    const int tid  = threadIdx.x;
    const int wave = tid >> 6, lane = tid & 63;
    const int quad = lane >> 4, l15 = lane & 15;
    const int m0 = blockIdx.y * 64, n0 = blockIdx.x * 64;
    const int mw = (wave & 1) * 32, nw = (wave >> 1) * 32;
    const int srow = tid >> 2, sseg = tid & 3;

    floatx4 P[2][2];
    #pragma unroll
    for (int f = 0; f < 2; f++)
        #pragma unroll
        for (int g = 0; g < 2; g++)
            P[f][g] = (floatx4){0.f, 0.f, 0.f, 0.f};

    for (int k0 = 0; k0 < K; k0 += 64) {
        const float* ap = A + (size_t)(m0 + srow) * K + k0 + sseg * 16;
        float4 a0 = *(const float4*)(ap);
        float4 a1 = *(const float4*)(ap + 4);
        float4 a2 = *(const float4*)(ap + 8);
        float4 a3 = *(const float4*)(ap + 12);
        union { unsigned short s[8]; short8 v; } p0, p1;
        p0.s[0] = f2bf(a0.x); p0.s[1] = f2bf(a0.y); p0.s[2] = f2bf(a0.z); p0.s[3] = f2bf(a0.w);
        p0.s[4] = f2bf(a1.x); p0.s[5] = f2bf(a1.y); p0.s[6] = f2bf(a1.z); p0.s[7] = f2bf(a1.w);
        p1.s[0] = f2bf(a2.x); p1.s[1] = f2bf(a2.y); p1.s[2] = f2bf(a2.z); p1.s[3] = f2bf(a2.w);
        p1.s[4] = f2bf(a3.x); p1.s[5] = f2bf(a3.y); p1.s[6] = f2bf(a3.z); p1.s[7] = f2bf(a3.w);
        *(short8*)&sA[srow][sseg * 16]     = p0.v;
        *(short8*)&sA[srow][sseg * 16 + 8] = p1.v;
        const unsigned short* wp = W + (size_t)(n0 + srow) * K + k0 + sseg * 16;
        *(short8*)&sW[srow][sseg * 16]     = *(const short8*)wp;
        *(short8*)&sW[srow][sseg * 16 + 8] = *(const short8*)(wp + 8);
        __syncthreads();
        #pragma unroll
        for (int kh = 0; kh < 2; kh++) {
            short8 af[2], wf[2];
            af[0] = *(short8*)&sA[mw + l15][kh * 32 + quad * 8];
            af[1] = *(short8*)&sA[mw + 16 + l15][kh * 32 + quad * 8];
            wf[0] = *(short8*)&sW[nw + l15][kh * 32 + quad * 8];
            wf[1] = *(short8*)&sW[nw + 16 + l15][kh * 32 + quad * 8];
            #pragma unroll
            for (int f = 0; f < 2; f++)
                #pragma unroll
                for (int g = 0; g < 2; g++)
                    P[f][g] = __builtin_amdgcn_mfma_f32_16x16x32_bf16(af[f], wf[g], P[f][g], 0, 0, 0);
        }
        __syncthreads();
    }
    #pragma unroll
    for (int f = 0; f < 2; f++)
        #pragma unroll
        for (int g = 0; g < 2; g++)
            #pragma unroll
            for (int r = 0; r < 4; r++) {
                int m = m0 + mw + 16 * f + quad * 4 + r;
                int n = n0 + nw + 16 * g + l15;
                float v = P[f][g][r] + bias[n];
                float a = A[(size_t)m * 512 + 256 + n];
                Cbf[(size_t)m * N + n] = f2bf(1.f / (1.f + expf(-v * a)));
            }
}

// ---------------- fused weight converts (one launch) ------------------------
__global__ __launch_bounds__(256)
void conv_multi(const float* __restrict__ s0, unsigned short* __restrict__ d0, // vis 4194304
                const float* __restrict__ s1, unsigned short* __restrict__ d1, // aud 1048576
                const float* __restrict__ s2, unsigned short* __restrict__ d2, // msv 786432
                const float* __restrict__ s3, unsigned short* __restrict__ d3, // msa 786432
                const float* __restrict__ s4, unsigned short* __restrict__ d4, // W1  393216
                const float* __restrict__ s5, unsigned short* __restrict__ d5) // W2  65536
{
    long long g = ((long long)blockIdx.x * 256 + threadIdx.x) * 8;
    const float* src; unsigned short* dst; long long off = g;
    if      (off < 4194304)                 { src = s0; dst = d0; }
    else if ((off = g - 4194304) < 1048576) { src = s1; dst = d1; }
    else if ((off = g - 5242880) < 786432)  { src = s2; dst = d2; }
    else if ((off = g - 6029312) < 786432)  { src = s3; dst = d3; }
    else if ((off = g - 6815744) < 393216)  { src = s4; dst = d4; }
    else if ((off = g - 7208960) < 65536)   { src = s5; dst = d5; }
    else return;
    float4 a = *(const float4*)(src + off);
    float4 b = *(const float4*)(src + off + 4);
    union { unsigned short s[8]; uint4 v; } o;
    o.s[0] = f2bf(a.x); o.s[1] = f2bf(a.y); o.s[2] = f2bf(a.z); o.s[3] = f2bf(a.w);
    o.s[4] = f2bf(b.x); o.s[5] = f2bf(b.y); o.s[6] = f2bf(b.z); o.s[7] = f2bf(b.w);
    *(uint4*)(dst + off) = o.v;
}

// ---------------- mmfa weight + bias pack (one launch) ----------------------
__global__ __launch_bounds__(256)
void pack_mmfa(const float* __restrict__ mW, const float* __restrict__ mb,
               unsigned short* __restrict__ Wqkv, unsigned short* __restrict__ Wqka,
               unsigned short* __restrict__ Wcva, unsigned short* __restrict__ Wcav,
               float* __restrict__ bqkv, float* __restrict__ bqka,
               float* __restrict__ bcva, float* __restrict__ bcav)
{
    int b = blockIdx.x;
    if (b < 2048) {
        int i = b * 256 + threadIdx.x;      // over 8*65536 elements
        int w = i >> 16, r = i & 65535;
        unsigned short s = f2bf(mW[i]);
        int row = r >> 8, col = r & 255;
        switch (w) {
            case 0: Wqkv[r] = s; break;
            case 1: Wqka[r] = s; break;
            case 2: Wqkv[65536 + r] = s; break;
            case 3: Wqka[65536 + r] = s; break;
            case 4: Wcva[row * 512 + col] = s; break;
            case 5: Wcva[row * 512 + 256 + col] = s; break;
            case 6: Wcav[row * 512 + col] = s; break;
            case 7: Wcav[row * 512 + 256 + col] = s; break;
        }
    } else {
        int i = threadIdx.x;
        for (int t = i; t < 512; t += 256) {
            int c = t & 255;
            bqkv[t] = mb[(t < 256 ? 0 : 512) + c];
            bqka[t] = mb[(t < 256 ? 256 : 768) + c];
        }
        bcva[i] = mb[1024 + i] + mb[1280 + i];
        bcav[i] = mb[1536 + i] + mb[1792 + i];
    }
}

// ---------------- bilinear: column-per-block, pipelined ---------------------
// grid (o=256, mh=2), 512 thr / 8 waves; wave owns i in [w*32, w*32+32).
// Double-buffered sA + deferred cross-wave reduce: ONE barrier per m-step.
__global__ __launch_bounds__(512, 4)
void bilinear_col(const unsigned short* __restrict__ cav, // [3072][256] bf16
                  const unsigned short* __restrict__ cva, // [3072][256] bf16
                  const float* __restrict__ Wf,           // [256][256][256] f32
                  float* __restrict__ outT)               // [256][3072] f32
{
    __shared__ short sA[2][64][264];
    __shared__ float sRed[2][8][64];
    const int tid  = threadIdx.x;
    const int wave = tid >> 6, lane = tid & 63;
    const int quad = lane >> 4, l15 = lane & 15;
    const int o     = blockIdx.x;
    const int mbase = blockIdx.y * 1536;
    const int i0    = wave * 32;

    // ---- load W_o fragments once (fp32 -> bf16 in-register)
    short8 Wr[2][8];
    {
        const float* wo = Wf + (size_t)o * 65536;
        #pragma unroll
        for (int f = 0; f < 2; f++) {
            const float* wrow = wo + (size_t)(i0 + 16 * f + l15) * 256 + quad * 8;
            #pragma unroll
            for (int s = 0; s < 8; s++) {
                float4 lo = *(const float4*)(wrow + s * 32);
                float4 hi = *(const float4*)(wrow + s * 32 + 4);
                union { unsigned short u[8]; short8 v; } p;
                p.u[0] = f2bf(lo.x); p.u[1] = f2bf(lo.y); p.u[2] = f2bf(lo.z); p.u[3] = f2bf(lo.w);
                p.u[4] = f2bf(hi.x); p.u[5] = f2bf(hi.y); p.u[6] = f2bf(hi.z); p.u[7] = f2bf(hi.w);
                Wr[f][s] = p.v;
            }
        }
    }

    const int srow = tid >> 3, sseg = tid & 7;
    // preload tile 0 into sA[0]
    {
        const unsigned short* src = cav + (size_t)(mbase + srow) * 256 + sseg * 32;
        #pragma unroll
        for (int u = 0; u < 4; u++)
            *(short8*)&sA[0][srow][sseg * 32 + u * 8] = *(const short8*)(src + u * 8);
    }
    __syncthreads();

    for (int ms = 0; ms <= 24; ms++) {
        const int cur = ms & 1;
        if (ms < 24) {
            const int m0 = mbase + ms * 64;
            const bool have_next = (ms < 23);
            // prefetch next cav tile into regs (in flight during MFMA)
            short8 stg[4];
            if (have_next) {
                const unsigned short* src = cav + (size_t)(m0 + 64 + srow) * 256 + sseg * 32;
                #pragma unroll
                for (int u = 0; u < 4; u++) stg[u] = *(const short8*)(src + u * 8);
            }
            // cva scattered loads (in flight during MFMA)
            uint2 raws[2][4];
            #pragma unroll
            for (int g = 0; g < 4; g++)
                #pragma unroll
                for (int f = 0; f < 2; f++)
                    raws[f][g] = *(const uint2*)(cva + (size_t)(m0 + 16 * g + l15) * 256
                                                      + i0 + 16 * f + 4 * quad);

            floatx4 P2[2][4];
            #pragma unroll
            for (int f = 0; f < 2; f++)
                #pragma unroll
                for (int g = 0; g < 4; g++)
                    P2[f][g] = (floatx4){0.f, 0.f, 0.f, 0.f};

            #pragma unroll
            for (int s = 0; s < 8; s++) {
                short8 bg[4];
                #pragma unroll
                for (int g = 0; g < 4; g++)
                    bg[g] = *(const short8*)&sA[cur][16 * g + l15][s * 32 + quad * 8];
                #pragma unroll
                for (int f = 0; f < 2; f++)
                    #pragma unroll
                    for (int g = 0; g < 4; g++)
                        P2[f][g] = __builtin_amdgcn_mfma_f32_16x16x32_bf16(Wr[f][s], bg[g], P2[f][g], 0, 0, 0);
            }

            float T[4] = {0.f, 0.f, 0.f, 0.f};
            #pragma unroll
            for (int g = 0; g < 4; g++)
                #pragma unroll
                for (int f = 0; f < 2; f++) {
                    uint2 raw = raws[f][g];
                    T[g] += bf2f((unsigned short)(raw.x & 0xffff)) * P2[f][g][0]
                          + bf2f((unsigned short)(raw.x >> 16))    * P2[f][g][1]
                          + bf2f((unsigned short)(raw.y & 0xffff)) * P2[f][g][2]
                          + bf2f((unsigned short)(raw.y >> 16))    * P2[f][g][3];
                }
            #pragma unroll
            for (int g = 0; g < 4; g++) {
                T[g] += __shfl_xor(T[g], 16);
                T[g] += __shfl_xor(T[g], 32);
            }
            if (quad == 0) {
                #pragma unroll
                for (int g = 0; g < 4; g++)
                    sRed[cur][wave][16 * g + l15] = T[g];
            }
            // store prefetched tile into the other buffer
            if (have_next) {
                #pragma unroll
                for (int u = 0; u < 4; u++)
                    *(short8*)&sA[cur ^ 1][srow][sseg * 32 + u * 8] = stg[u];
            }
        }
        // drain previous m-step's reduction (sRed[cur^1], synced last iter)
        if (ms > 0 && tid < 64) {
            const int pb = (ms - 1) & 1;
            float acc = sRed[pb][0][tid] + sRed[pb][1][tid] + sRed[pb][2][tid]
                      + sRed[pb][3][tid] + sRed[pb][4][tid] + sRed[pb][5][tid]
                      + sRed[pb][6][tid] + sRed[pb][7][tid];
            outT[(size_t)o * 3072 + mbase + (ms - 1) * 64 + tid] = acc;
        }
        __syncthreads();
    }
}

// ---------------- attention (packed q/k [3072][512], packed alpha out) ------
__global__ __launch_bounds__(256)
void attn_packed(const float* __restrict__ qkv, const float* __restrict__ qka,
                 const float* __restrict__ xv, const float* __restrict__ xa,
                 float* __restrict__ al_v, float* __restrict__ al_a)
{
    const int b    = blockIdx.x;
    const int tid  = threadIdx.x;
    const int wave = tid >> 6;
    const int lane = tid & 63;
    __shared__ float att[4][3][3];
    const size_t b512 = (size_t)b * 1536;
    const size_t b768 = (size_t)b * 768;
    const float* Qs[4] = {qkv, qkv, qka, qka};
    const float* Ks[4] = {qka + 256, qkv + 256, qkv + 256, qka + 256};
    const float* Xs[4] = {xa, xv, xv, xa};
    float*       Os[4] = {al_v, al_v + 256, al_a, al_a + 256};
    const float* q = Qs[wave] + b512;
    const float* k = Ks[wave] + b512;
    float part[9] = {};
    for (int d = lane; d < 256; d += 64) {
        float q0 = q[d], q1 = q[512 + d], q2 = q[1024 + d];
        float k0 = k[d], k1 = k[512 + d], k2 = k[1024 + d];
        part[0] += q0 * k0; part[1] += q0 * k1; part[2] += q0 * k2;
        part[3] += q1 * k0; part[4] += q1 * k1; part[5] += q1 * k2;
        part[6] += q2 * k0; part[7] += q2 * k1; part[8] += q2 * k2;
    }
    #pragma unroll
    for (int off = 32; off > 0; off >>= 1)
        #pragma unroll
        for (int i = 0; i < 9; i++) part[i] += __shfl_down(part[i], off);
    if (lane == 0) {
        #pragma unroll
        for (int s = 0; s < 3; s++) {
            float a0 = part[s * 3], a1 = part[s * 3 + 1], a2 = part[s * 3 + 2];
            float mx = fmaxf(a0, fmaxf(a1, a2));
            float e0 = expf(a0 - mx), e1 = expf(a1 - mx), e2 = expf(a2 - mx);
            float inv = NORM / (e0 + e1 + e2);
            att[wave][s][0] = e0 * inv;
            att[wave][s][1] = e1 * inv;
            att[wave][s][2] = e2 * inv;
        }
    }
    __syncthreads();
    const int d = tid;
    #pragma unroll
    for (int w = 0; w < 4; w++) {
        const float* x = Xs[w] + b768;
        float x0 = x[d], x1 = x[256 + d], x2 = x[512 + d];
        float* o = Os[w] + b512;
        #pragma unroll
        for (int s = 0; s < 3; s++)
            o[s * 512 + d] = att[w][s][0] * x0 + att[w][s][1] * x1 + att[w][s][2] * x2;
    }
}

// ---------------- elementwise mix -------------------------------------------
__global__ void ew_mix(const float* __restrict__ logitsT, const float* __restrict__ xv,
                       const float* __restrict__ xa, const float* __restrict__ bv,
                       const float* __restrict__ ba, const float* __restrict__ tc,
                       float* __restrict__ outv, float* __restrict__ outa, int n)
{
    int i = blockIdx.x * 256 + threadIdx.x;
    if (i < n) {
        int m = i >> 8, o = i & 255;
        float j = 1.f / (1.f + expf(-logitsT[(size_t)o * 3072 + m]));
        float M = tc[0] * j * xv[i] + (1.f - j) * xa[i];
        outv[i] = M * bv[i];
        outa[i] = M * ba[i];
    }
}

// ---------------- fused classifier: p = relu(f @ W1^T) @ W2^T ---------------
// grid (16, 2); block 256 thr = 64 rows x 4 j-groups.
__global__ __launch_bounds__(256)
void cls_fused(const float* __restrict__ fv, const float* __restrict__ fa,
               const float* __restrict__ Wv1, const float* __restrict__ Wv2,
               const float* __restrict__ Wa1, const float* __restrict__ Wa2,
               float* __restrict__ pv, float* __restrict__ pa)
{
    const int z = blockIdx.y;
    const float* F  = z ? fa  : fv;
    const float* W1 = z ? Wa1 : Wv1;   // [32][128]
    const float* W2 = z ? Wa2 : Wv2;   // [10][32]
    float* Pp       = z ? pa  : pv;
    __shared__ float sX[64][132];
    __shared__ float sW1[32][133];
    __shared__ float sH[64][33];
    __shared__ float sW2[320];
    const int tid = threadIdx.x;
    const int r0  = blockIdx.x * 64;
    for (int u = tid; u < 64 * 32; u += 256) {
        int row = u >> 5, seg = u & 31;
        *(float4*)&sX[row][seg * 4] = *(const float4*)(F + (size_t)(r0 + row) * 128 + seg * 4);
    }
    for (int u = tid; u < 32 * 128; u += 256) {
        int row = u >> 7, k = u & 127;
        sW1[row][k] = W1[row * 128 + k];
    }
    if (tid < 80) ((float4*)sW2)[tid] = ((const float4*)W2)[tid];
    __syncthreads();
    const int r = tid >> 2, jg = (tid & 3) * 8;
    float h[8] = {};
    for (int k = 0; k < 128; k++) {
        float x = sX[r][k];
        #pragma unroll
        for (int j = 0; j < 8; j++) h[j] += x * sW1[jg + j][k];
    }
    #pragma unroll
    for (int j = 0; j < 8; j++) sH[r][jg + j] = fmaxf(h[j], 0.f);
    __syncthreads();
    for (int u = tid; u < 640; u += 256) {
        int row = u / 10, oo = u % 10;
        float acc = 0.f;
        #pragma unroll
        for (int j = 0; j < 32; j++) acc += sH[row][j] * sW2[oo * 32 + j];
        Pp[(size_t)(r0 + row) * 10 + oo] = acc;
    }
}

// ---------------------------------------------------------------------------
extern "C" void kernel_launch(void* const* d_in, const int* in_sizes, int n_in,
                              void* d_out, int out_size, void* d_ws, size_t ws_size,
                              hipStream_t stream)
{
    const float* img    = (const float*)d_in[0];
    const float* audio  = (const float*)d_in[1];
    const float* vis_W  = (const float*)d_in[2];
    const float* vis_b  = (const float*)d_in[3];
    const float* aud_W  = (const float*)d_in[4];
    const float* aud_b  = (const float*)d_in[5];
    const float* msv_W  = (const float*)d_in[6];
    const float* msv_b  = (const float*)d_in[7];
    const float* msa_W  = (const float*)d_in[8];
    const float* msa_b  = (const float*)d_in[9];
    const float* mmfa_W = (const float*)d_in[10];
    const float* mmfa_b = (const float*)d_in[11];
    const float* bil_W  = (const float*)d_in[12];
    const float* t_c    = (const float*)d_in[13];
    const float* out_W1 = (const float*)d_in[14];
    const float* out_b1 = (const float*)d_in[15];
    const float* out_W2 = (const float*)d_in[16];
    const float* out_b2 = (const float*)d_in[17];
    const float* clsv_W1 = (const float*)d_in[18];
    const float* clsv_W2 = (const float*)d_in[19];
    const float* clsa_W1 = (const float*)d_in[20];
    const float* clsa_W2 = (const float*)d_in[21];
    float* out = (float*)d_out;
    float* ws  = (float*)d_ws;

    constexpr size_t SD = 3072 * 256; // 786432
    // ---- scratch region S (8,388,608 floats)
    float* S = ws;
    // pack phase (dead once stage 1 begins)
    unsigned short* visbf = (unsigned short*)(S + 2097152);
    unsigned short* audbf = (unsigned short*)(S + 4194304);
    unsigned short* msvbf = (unsigned short*)(S + 4718592);
    unsigned short* msabf = (unsigned short*)(S + 5111808);
    float* vis  = S;
    float* aud  = S + 1048576;
    // stage phase
    float* qkv  = S;                  // [0, 1572864)
    float* qka  = S + 1572864;        // [1572864, 3145728)
    float* al_v = S + 3145728;
    float* al_a = S + 4718592;
    // end phase (qkv/qka dead)
    float* ovb  = S;                  // [0, SD)
    float* oab  = S + SD;             // [SD, 2SD)
    float* hv1  = S + 2 * SD;         // 524288
    float* hv2  = S + 2 * SD + 524288;
    // ---- persistent region
    float* P = ws + 8388608;
    float* v_ms    = P;
    float* a_ms    = P + SD;
    float* x_v2    = P + 2 * SD;
    float* x_a2    = P + 3 * SD;
    float* logitsT = P + 4 * SD;                                  // [256][3072]
    unsigned short* c_va = (unsigned short*)(P + 5 * SD);         // [3072][256] bf16
    unsigned short* c_av = (unsigned short*)(P + 5 * SD + SD / 2);
    unsigned short* Wqkv = (unsigned short*)(P + 6 * SD);
    unsigned short* Wqka = Wqkv + 131072;
    unsigned short* Wcva = Wqka + 131072;
    unsigned short* Wcav = Wcva + 131072;
    float* bqkv = P + 6 * SD + 262144;
    float* bqka = bqkv + 512;
    float* bcva = bqka + 512;
    float* bcav = bcva + 256;
    unsigned short* W1bf = (unsigned short*)(bcav + 256);         // 393216 sh
    unsigned short* W2bf = W1bf + 393216;                         //  65536 sh
    // end of P: 8388608 + 6*SD + 262144 + 1536 + 229376 = 13,600,256 fl (54.4MB)

    // ---- weight packing: 2 launches
    conv_multi<<<3552, 256, 0, stream>>>(vis_W, visbf, aud_W, audbf,
                                         msv_W, msvbf, msa_W, msabf,
                                         out_W1, W1bf, out_W2, W2bf);
    pack_mmfa<<<2049, 256, 0, stream>>>(mmfa_W, mmfa_b, Wqkv, Wqka, Wcva, Wcav,
                                        bqkv, bqka, bcva, bcav);

    // ---- encoders + multiscale
    gemm_mfma_z<1><<<dim3(16, 16, 1), 256, 0, stream>>>(
        img, img, visbf, visbf, vis_b, vis_b, vis, vis, 1024, 1024, 4096);
    gemm_mfma_z<1><<<dim3(16, 16, 1), 256, 0, stream>>>(
        audio, audio, audbf, audbf, aud_b, aud_b, aud, aud, 1024, 1024, 1024);
    gemm_mfma_z<1><<<dim3(12, 16, 2), 256, 0, stream>>>(
        vis, aud, msvbf, msabf, msv_b, msa_b, v_ms, a_ms, 1024, 768, 1024);

    const int EW_N = (int)SD;
    const int EW_G = (EW_N + 255) / 256;

    auto mmfa = [&](const float* xv, const float* xa, float* outv, float* outa) {
        gemm_mfma_z<0><<<dim3(8, 48, 2), 256, 0, stream>>>(
            xv, xa, Wqkv, Wqka, bqkv, bqka, qkv, qka, 3072, 512, 256);
        attn_packed<<<1024, 256, 0, stream>>>(qkv, qka, xv, xa, al_v, al_a);
        gemm_sigm_z<<<dim3(4, 48, 2), 256, 0, stream>>>(
            al_v, al_a, Wcva, Wcav, bcva, bcav, c_va, c_av, 3072, 256, 512);
        bilinear_col<<<dim3(256, 2), 512, 0, stream>>>(c_av, c_va, bil_W, logitsT);
        ew_mix<<<EW_G, 256, 0, stream>>>(logitsT, xv, xa, v_ms, a_ms, t_c,
                                         outv, outa, EW_N);
    };

    mmfa(v_ms, a_ms, x_v2, x_a2);   // M1 stage
    mmfa(x_v2, x_a2, ovb, oab);     // M2 stage

    float* fv = out;
    float* fa = out + 1024 * 128;
    float* pv = out + 2 * 1024 * 128;
    float* pa = pv + 1024 * 10;

    // ---- out_layer (z-fused) + fused classifiers
    gemm_mfma_z<1><<<dim3(8, 16, 2), 256, 0, stream>>>(
        ovb, oab, W1bf, W1bf, out_b1, out_b1, hv1, hv2, 1024, 512, 768);
    gemm_mfma_z<0><<<dim3(2, 16, 2), 256, 0, stream>>>(
        hv1, hv2, W2bf, W2bf, out_b2, out_b2, fv, fa, 1024, 128, 512);
    cls_fused<<<dim3(16, 2), 256, 0, stream>>>(fv, fa, clsv_W1, clsv_W2,
                                               clsa_W1, clsa_W2, pv, pa);

    (void)in_sizes; (void)n_in; (void)out_size; (void)ws_size;
}

// Round 7
// 781.321 us; speedup vs baseline: 1.1164x; 1.1164x over previous
//
#include <hip/hip_runtime.h>
#include <math.h>

// ---------------------------------------------------------------------------
// CrossModal_NN — round 7: round-6 fusions kept; bilinear reverted to the
// proven round-5 structure (no dbuf — r6's version spilled to scratch,
// WRITE_SIZE 30->360 MB) and launched at grid (256,4) = 4 blocks/CU
// (LDS 4x35840=143KB<160KB, VGPR 64) to double latency-hiding overlap.
// ---------------------------------------------------------------------------

typedef short short8   __attribute__((ext_vector_type(8)));
typedef float floatx4  __attribute__((ext_vector_type(4)));

constexpr float NORM = 0.0625f; // 1/sqrt(256), applied AFTER softmax (faithful)

__device__ __forceinline__ unsigned short f2bf(float f) {
    union { float f; unsigned int u; } v; v.f = f;
    unsigned int r = v.u + 0x7fffu + ((v.u >> 16) & 1u); // RNE
    return (unsigned short)(r >> 16);
}
__device__ __forceinline__ float bf2f(unsigned short s) {
    union { unsigned int u; float f; } v; v.u = ((unsigned int)s) << 16;
    return v.f;
}

// ---------------- bf16 MFMA GEMM (z-fused pair): C = act(A @ W^T + bias) ----
template<int ACT>
__global__ __launch_bounds__(256)
void gemm_mfma_z(const float* __restrict__ A0, const float* __restrict__ A1,
                 const unsigned short* __restrict__ Wp0,
                 const unsigned short* __restrict__ Wp1,
                 const float* __restrict__ b0, const float* __restrict__ b1,
                 float* __restrict__ C0, float* __restrict__ C1,
                 int M, int N, int K)
{
    const float* A = blockIdx.z ? A1 : A0;
    const unsigned short* W = blockIdx.z ? Wp1 : Wp0;
    const float* bias = blockIdx.z ? b1 : b0;
    float* C = blockIdx.z ? C1 : C0;

    __shared__ short sA[64][72];
    __shared__ short sW[64][72];
    const int tid  = threadIdx.x;
    const int wave = tid >> 6, lane = tid & 63;
    const int quad = lane >> 4, l15 = lane & 15;
    const int m0 = blockIdx.y * 64, n0 = blockIdx.x * 64;
    const int mw = (wave & 1) * 32, nw = (wave >> 1) * 32;
    const int srow = tid >> 2, sseg = tid & 3;

    floatx4 P[2][2];
    #pragma unroll
    for (int f = 0; f < 2; f++)
        #pragma unroll
        for (int g = 0; g < 2; g++)
            P[f][g] = (floatx4){0.f, 0.f, 0.f, 0.f};

    for (int k0 = 0; k0 < K; k0 += 64) {
        const float* ap = A + (size_t)(m0 + srow) * K + k0 + sseg * 16;
        float4 a0 = *(const float4*)(ap);
        float4 a1 = *(const float4*)(ap + 4);
        float4 a2 = *(const float4*)(ap + 8);
        float4 a3 = *(const float4*)(ap + 12);
        union { unsigned short s[8]; short8 v; } p0, p1;
        p0.s[0] = f2bf(a0.x); p0.s[1] = f2bf(a0.y); p0.s[2] = f2bf(a0.z); p0.s[3] = f2bf(a0.w);
        p0.s[4] = f2bf(a1.x); p0.s[5] = f2bf(a1.y); p0.s[6] = f2bf(a1.z); p0.s[7] = f2bf(a1.w);
        p1.s[0] = f2bf(a2.x); p1.s[1] = f2bf(a2.y); p1.s[2] = f2bf(a2.z); p1.s[3] = f2bf(a2.w);
        p1.s[4] = f2bf(a3.x); p1.s[5] = f2bf(a3.y); p1.s[6] = f2bf(a3.z); p1.s[7] = f2bf(a3.w);
        *(short8*)&sA[srow][sseg * 16]     = p0.v;
        *(short8*)&sA[srow][sseg * 16 + 8] = p1.v;
        const unsigned short* wp = W + (size_t)(n0 + srow) * K + k0 + sseg * 16;
        *(short8*)&sW[srow][sseg * 16]     = *(const short8*)wp;
        *(short8*)&sW[srow][sseg * 16 + 8] = *(const short8*)(wp + 8);
        __syncthreads();
        #pragma unroll
        for (int kh = 0; kh < 2; kh++) {
            short8 af[2], wf[2];
            af[0] = *(short8*)&sA[mw + l15][kh * 32 + quad * 8];
            af[1] = *(short8*)&sA[mw + 16 + l15][kh * 32 + quad * 8];
            wf[0] = *(short8*)&sW[nw + l15][kh * 32 + quad * 8];
            wf[1] = *(short8*)&sW[nw + 16 + l15][kh * 32 + quad * 8];
            #pragma unroll
            for (int f = 0; f < 2; f++)
                #pragma unroll
                for (int g = 0; g < 2; g++)
                    P[f][g] = __builtin_amdgcn_mfma_f32_16x16x32_bf16(af[f], wf[g], P[f][g], 0, 0, 0);
        }
        __syncthreads();
    }
    #pragma unroll
    for (int f = 0; f < 2; f++)
        #pragma unroll
        for (int g = 0; g < 2; g++)
            #pragma unroll
            for (int r = 0; r < 4; r++) {
                int m = m0 + mw + 16 * f + quad * 4 + r;
                int n = n0 + nw + 16 * g + l15;
                float v = P[f][g][r] + bias[n];
                if (ACT) v = fmaxf(v, 0.f);
                C[(size_t)m * N + n] = v;
            }
}

// ---- z-fused GEMM with sigmoid(G*alpha)->bf16 epilogue ---------------------
__global__ __launch_bounds__(256)
void gemm_sigm_z(const float* __restrict__ A0, const float* __restrict__ A1,
                 const unsigned short* __restrict__ Wp0,
                 const unsigned short* __restrict__ Wp1,
                 const float* __restrict__ b0, const float* __restrict__ b1,
                 unsigned short* __restrict__ O0, unsigned short* __restrict__ O1,
                 int M, int N, int K)
{
    const float* A = blockIdx.z ? A1 : A0;           // alpha lives in A[.,256:512]
    const unsigned short* W = blockIdx.z ? Wp1 : Wp0;
    const float* bias = blockIdx.z ? b1 : b0;
    unsigned short* Cbf = blockIdx.z ? O1 : O0;

    __shared__ short sA[64][72];
    __shared__ short sW[64][72];
    const int tid  = threadIdx.x;
    const int wave = tid >> 6, lane = tid & 63;
    const int quad = lane >> 4, l15 = lane & 15;
    const int m0 = blockIdx.y * 64, n0 = blockIdx.x * 64;
    const int mw = (wave & 1) * 32, nw = (wave >> 1) * 32;
    const int srow = tid >> 2, sseg = tid & 3;

    floatx4 P[2][2];
    #pragma unroll
    for (int f = 0; f < 2; f++)
        #pragma unroll
        for (int g = 0; g < 2; g++)
            P[f][g] = (floatx4){0.f, 0.f, 0.f, 0.f};

    for (int k0 = 0; k0 < K; k0 += 64) {
        const float* ap = A + (size_t)(m0 + srow) * K + k0 + sseg * 16;
        float4 a0 = *(const float4*)(ap);
        float4 a1 = *(const float4*)(ap + 4);
        float4 a2 = *(const float4*)(ap + 8);
        float4 a3 = *(const float4*)(ap + 12);
        union { unsigned short s[8]; short8 v; } p0, p1;
        p0.s[0] = f2bf(a0.x); p0.s[1] = f2bf(a0.y); p0.s[2] = f2bf(a0.z); p0.s[3] = f2bf(a0.w);
        p0.s[4] = f2bf(a1.x); p0.s[5] = f2bf(a1.y); p0.s[6] = f2bf(a1.z); p0.s[7] = f2bf(a1.w);
        p1.s[0] = f2bf(a2.x); p1.s[1] = f2bf(a2.y); p1.s[2] = f2bf(a2.z); p1.s[3] = f2bf(a2.w);
        p1.s[4] = f2bf(a3.x); p1.s[5] = f2bf(a3.y); p1.s[6] = f2bf(a3.z); p1.s[7] = f2bf(a3.w);
        *(short8*)&sA[srow][sseg * 16]     = p0.v;
        *(short8*)&sA[srow][sseg * 16 + 8] = p1.v;
        const unsigned short* wp = W + (size_t)(n0 + srow) * K + k0 + sseg * 16;
        *(short8*)&sW[srow][sseg * 16]     = *(const short8*)wp;
        *(short8*)&sW[srow][sseg * 16 + 8] = *(const short8*)(wp + 8);
        __syncthreads();
        #pragma unroll
        for (int kh = 0; kh < 2; kh++) {
            short8 af[2], wf[2];
            af[0] = *(short8*)&sA[mw + l15][kh * 32 + quad * 8];
            af[1] = *(short8*)&sA[mw + 16 + l15][kh * 32 + quad * 8];
            wf[0] = *(short8*)&sW[nw + l15][kh * 32 + quad * 8];
            wf[1] = *(short8*)&sW[nw + 16 + l15][kh * 32 + quad * 8];
            #pragma unroll
            for (int f = 0; f < 2; f++)
                #pragma unroll
                for (int g = 0; g < 2; g++)
                    P[f][g] = __builtin_amdgcn_mfma_f32_16x16x32_bf16(af[f], wf[g], P[f][g], 0, 0, 0);
        }
        __syncthreads();
    }
    #pragma unroll
    for (int f = 0; f < 2; f++)
        #pragma unroll
        for (int g = 0; g < 2; g++)
            #pragma unroll
            for (int r = 0; r < 4; r++) {
                int m = m0 + mw + 16 * f + quad * 4 + r;
                int n = n0 + nw + 16 * g + l15;
                float v = P[f][g][r] + bias[n];
                float a = A[(size_t)m * 512 + 256 + n];
                Cbf[(size_t)m * N + n] = f2bf(1.f / (1.f + expf(-v * a)));
            }
}

// ---------------- fused weight converts (one launch) ------------------------
__global__ __launch_bounds__(256)
void conv_multi(const float* __restrict__ s0, unsigned short* __restrict__ d0, // vis 4194304
                const float* __restrict__ s1, unsigned short* __restrict__ d1, // aud 1048576
                const float* __restrict__ s2, unsigned short* __restrict__ d2, // msv 786432
                const float* __restrict__ s3, unsigned short* __restrict__ d3, // msa 786432
                const float* __restrict__ s4, unsigned short* __restrict__ d4, // W1  393216
                const float* __restrict__ s5, unsigned short* __restrict__ d5) // W2  65536
{
    long long g = ((long long)blockIdx.x * 256 + threadIdx.x) * 8;
    const float* src; unsigned short* dst; long long off = g;
    if      (off < 4194304)                 { src = s0; dst = d0; }
    else if ((off = g - 4194304) < 1048576) { src = s1; dst = d1; }
    else if ((off = g - 5242880) < 786432)  { src = s2; dst = d2; }
    else if ((off = g - 6029312) < 786432)  { src = s3; dst = d3; }
    else if ((off = g - 6815744) < 393216)  { src = s4; dst = d4; }
    else if ((off = g - 7208960) < 65536)   { src = s5; dst = d5; }
    else return;
    float4 a = *(const float4*)(src + off);
    float4 b = *(const float4*)(src + off + 4);
    union { unsigned short s[8]; uint4 v; } o;
    o.s[0] = f2bf(a.x); o.s[1] = f2bf(a.y); o.s[2] = f2bf(a.z); o.s[3] = f2bf(a.w);
    o.s[4] = f2bf(b.x); o.s[5] = f2bf(b.y); o.s[6] = f2bf(b.z); o.s[7] = f2bf(b.w);
    *(uint4*)(dst + off) = o.v;
}

// ---------------- mmfa weight + bias pack (one launch) ----------------------
__global__ __launch_bounds__(256)
void pack_mmfa(const float* __restrict__ mW, const float* __restrict__ mb,
               unsigned short* __restrict__ Wqkv, unsigned short* __restrict__ Wqka,
               unsigned short* __restrict__ Wcva, unsigned short* __restrict__ Wcav,
               float* __restrict__ bqkv, float* __restrict__ bqka,
               float* __restrict__ bcva, float* __restrict__ bcav)
{
    int b = blockIdx.x;
    if (b < 2048) {
        int i = b * 256 + threadIdx.x;      // over 8*65536 elements
        int w = i >> 16, r = i & 65535;
        unsigned short s = f2bf(mW[i]);
        int row = r >> 8, col = r & 255;
        switch (w) {
            case 0: Wqkv[r] = s; break;
            case 1: Wqka[r] = s; break;
            case 2: Wqkv[65536 + r] = s; break;
            case 3: Wqka[65536 + r] = s; break;
            case 4: Wcva[row * 512 + col] = s; break;
            case 5: Wcva[row * 512 + 256 + col] = s; break;
            case 6: Wcav[row * 512 + col] = s; break;
            case 7: Wcav[row * 512 + 256 + col] = s; break;
        }
    } else {
        int i = threadIdx.x;
        for (int t = i; t < 512; t += 256) {
            int c = t & 255;
            bqkv[t] = mb[(t < 256 ? 0 : 512) + c];
            bqka[t] = mb[(t < 256 ? 256 : 768) + c];
        }
        bcva[i] = mb[1024 + i] + mb[1280 + i];
        bcav[i] = mb[1536 + i] + mb[1792 + i];
    }
}

// ---------------- bilinear: column-per-block (round-5 structure) ------------
// grid (o=256, mq=4), 512 thr / 8 waves; wave owns i in [w*32, w*32+32).
// W_o frags in VGPRs (Wr[2][8] = 64 VGPR), cav tile via LDS. 12 m-steps.
__global__ __launch_bounds__(512, 4)
void bilinear_col(const unsigned short* __restrict__ cav, // [3072][256] bf16
                  const unsigned short* __restrict__ cva, // [3072][256] bf16
                  const float* __restrict__ Wf,           // [256][256][256] f32
                  float* __restrict__ outT)               // [256][3072] f32
{
    __shared__ short sA[64][264];
    __shared__ float sRed[8][64];
    const int tid  = threadIdx.x;
    const int wave = tid >> 6, lane = tid & 63;
    const int quad = lane >> 4, l15 = lane & 15;
    const int o     = blockIdx.x;
    const int mbase = blockIdx.y * 768;
    const int i0    = wave * 32;

    // ---- load W_o fragments once (fp32 -> bf16 in-register)
    short8 Wr[2][8];
    {
        const float* wo = Wf + (size_t)o * 65536;
        #pragma unroll
        for (int f = 0; f < 2; f++) {
            const float* wrow = wo + (size_t)(i0 + 16 * f + l15) * 256 + quad * 8;
            #pragma unroll
            for (int s = 0; s < 8; s++) {
                float4 lo = *(const float4*)(wrow + s * 32);
                float4 hi = *(const float4*)(wrow + s * 32 + 4);
                union { unsigned short u[8]; short8 v; } p;
                p.u[0] = f2bf(lo.x); p.u[1] = f2bf(lo.y); p.u[2] = f2bf(lo.z); p.u[3] = f2bf(lo.w);
                p.u[4] = f2bf(hi.x); p.u[5] = f2bf(hi.y); p.u[6] = f2bf(hi.z); p.u[7] = f2bf(hi.w);
                Wr[f][s] = p.v;
            }
        }
    }

    const int srow = tid >> 3, sseg = tid & 7;
    for (int ms = 0; ms < 12; ms++) {
        const int m0 = mbase + ms * 64;
        __syncthreads();   // prev-step sA readers done
        {
            const unsigned short* src = cav + (size_t)(m0 + srow) * 256 + sseg * 32;
            #pragma unroll
            for (int u = 0; u < 4; u++)
                *(short8*)&sA[srow][sseg * 32 + u * 8] = *(const short8*)(src + u * 8);
        }
        __syncthreads();

        // issue cva loads early (overlap with MFMA burst)
        uint2 raws[2][4];
        #pragma unroll
        for (int g = 0; g < 4; g++)
            #pragma unroll
            for (int f = 0; f < 2; f++)
                raws[f][g] = *(const uint2*)(cva + (size_t)(m0 + 16 * g + l15) * 256
                                                  + i0 + 16 * f + 4 * quad);

        floatx4 P2[2][4];
        #pragma unroll
        for (int f = 0; f < 2; f++)
            #pragma unroll
            for (int g = 0; g < 4; g++)
                P2[f][g] = (floatx4){0.f, 0.f, 0.f, 0.f};

        #pragma unroll
        for (int s = 0; s < 8; s++) {
            short8 bg[4];
            #pragma unroll
            for (int g = 0; g < 4; g++)
                bg[g] = *(const short8*)&sA[16 * g + l15][s * 32 + quad * 8];
            #pragma unroll
            for (int f = 0; f < 2; f++)
                #pragma unroll
                for (int g = 0; g < 4; g++)
                    P2[f][g] = __builtin_amdgcn_mfma_f32_16x16x32_bf16(Wr[f][s], bg[g], P2[f][g], 0, 0, 0);
        }

        float T[4] = {0.f, 0.f, 0.f, 0.f};
        #pragma unroll
        for (int g = 0; g < 4; g++)
            #pragma unroll
            for (int f = 0; f < 2; f++) {
                uint2 raw = raws[f][g];
                T[g] += bf2f((unsigned short)(raw.x & 0xffff)) * P2[f][g][0]
                      + bf2f((unsigned short)(raw.x >> 16))    * P2[f][g][1]
                      + bf2f((unsigned short)(raw.y & 0xffff)) * P2[f][g][2]
                      + bf2f((unsigned short)(raw.y >> 16))    * P2[f][g][3];
            }
        #pragma unroll
        for (int g = 0; g < 4; g++) {
            T[g] += __shfl_xor(T[g], 16);
            T[g] += __shfl_xor(T[g], 32);
        }
        if (quad == 0) {
            #pragma unroll
            for (int g = 0; g < 4; g++)
                sRed[wave][16 * g + l15] = T[g];
        }
        __syncthreads();
        if (tid < 64) {
            float acc = sRed[0][tid] + sRed[1][tid] + sRed[2][tid] + sRed[3][tid]
                      + sRed[4][tid] + sRed[5][tid] + sRed[6][tid] + sRed[7][tid];
            outT[(size_t)o * 3072 + m0 + tid] = acc;
        }
    }
}

// ---------------- attention (packed q/k [3072][512], packed alpha out) ------
__global__ __launch_bounds__(256)
void attn_packed(const float* __restrict__ qkv, const float* __restrict__ qka,
                 const float* __restrict__ xv, const float* __restrict__ xa,
                 float* __restrict__ al_v, float* __restrict__ al_a)
{
    const int b    = blockIdx.x;
    const int tid  = threadIdx.x;
    const int wave = tid >> 6;
    const int lane = tid & 63;
    __shared__ float att[4][3][3];
    const size_t b512 = (size_t)b * 1536;
    const size_t b768 = (size_t)b * 768;
    const float* Qs[4] = {qkv, qkv, qka, qka};
    const float* Ks[4] = {qka + 256, qkv + 256, qkv + 256, qka + 256};
    const float* Xs[4] = {xa, xv, xv, xa};
    float*       Os[4] = {al_v, al_v + 256, al_a, al_a + 256};
    const float* q = Qs[wave] + b512;
    const float* k = Ks[wave] + b512;
    float part[9] = {};
    for (int d = lane; d < 256; d += 64) {
        float q0 = q[d], q1 = q[512 + d], q2 = q[1024 + d];
        float k0 = k[d], k1 = k[512 + d], k2 = k[1024 + d];
        part[0] += q0 * k0; part[1] += q0 * k1; part[2] += q0 * k2;
        part[3] += q1 * k0; part[4] += q1 * k1; part[5] += q1 * k2;
        part[6] += q2 * k0; part[7] += q2 * k1; part[8] += q2 * k2;
    }
    #pragma unroll
    for (int off = 32; off > 0; off >>= 1)
        #pragma unroll
        for (int i = 0; i < 9; i++) part[i] += __shfl_down(part[i], off);
    if (lane == 0) {
        #pragma unroll
        for (int s = 0; s < 3; s++) {
            float a0 = part[s * 3], a1 = part[s * 3 + 1], a2 = part[s * 3 + 2];
            float mx = fmaxf(a0, fmaxf(a1, a2));
            float e0 = expf(a0 - mx), e1 = expf(a1 - mx), e2 = expf(a2 - mx);
            float inv = NORM / (e0 + e1 + e2);
            att[wave][s][0] = e0 * inv;
            att[wave][s][1] = e1 * inv;
            att[wave][s][2] = e2 * inv;
        }
    }
    __syncthreads();
    const int d = tid;
    #pragma unroll
    for (int w = 0; w < 4; w++) {
        const float* x = Xs[w] + b768;
        float x0 = x[d], x1 = x[256 + d], x2 = x[512 + d];
        float* o = Os[w] + b512;
        #pragma unroll
        for (int s = 0; s < 3; s++)
            o[s * 512 + d] = att[w][s][0] * x0 + att[w][s][1] * x1 + att[w][s][2] * x2;
    }
}

// ---------------- elementwise mix -------------------------------------------
__global__ void ew_mix(const float* __restrict__ logitsT, const float* __restrict__ xv,
                       const float* __restrict__ xa, const float* __restrict__ bv,
                       const float* __restrict__ ba, const float* __restrict__ tc,
                       float* __restrict__ outv, float* __restrict__ outa, int n)
{
    int i = blockIdx.x * 256 + threadIdx.x;
    if (i < n) {
        int m = i >> 8, o = i & 255;
        float j = 1.f / (1.f + expf(-logitsT[(size_t)o * 3072 + m]));
        float M = tc[0] * j * xv[i] + (1.f - j) * xa[i];
        outv[i] = M * bv[i];
        outa[i] = M * ba[i];
    }
}

// ---------------- fused classifier: p = relu(f @ W1^T) @ W2^T ---------------
__global__ __launch_bounds__(256)
void cls_fused(const float* __restrict__ fv, const float* __restrict__ fa,
               const float* __restrict__ Wv1, const float* __restrict__ Wv2,
               const float* __restrict__ Wa1, const float* __restrict__ Wa2,
               float* __restrict__ pv, float* __restrict__ pa)
{
    const int z = blockIdx.y;
    const float* F  = z ? fa  : fv;
    const float* W1 = z ? Wa1 : Wv1;   // [32][128]
    const float* W2 = z ? Wa2 : Wv2;   // [10][32]
    float* Pp       = z ? pa  : pv;
    __shared__ float sX[64][132];
    __shared__ float sW1[32][133];
    __shared__ float sH[64][33];
    __shared__ float sW2[320];
    const int tid = threadIdx.x;
    const int r0  = blockIdx.x * 64;
    for (int u = tid; u < 64 * 32; u += 256) {
        int row = u >> 5, seg = u & 31;
        *(float4*)&sX[row][seg * 4] = *(const float4*)(F + (size_t)(r0 + row) * 128 + seg * 4);
    }
    for (int u = tid; u < 32 * 128; u += 256) {
        int row = u >> 7, k = u & 127;
        sW1[row][k] = W1[row * 128 + k];
    }
    if (tid < 80) ((float4*)sW2)[tid] = ((const float4*)W2)[tid];
    __syncthreads();
    const int r = tid >> 2, jg = (tid & 3) * 8;
    float h[8] = {};
    for (int k = 0; k < 128; k++) {
        float x = sX[r][k];
        #pragma unroll
        for (int j = 0; j < 8; j++) h[j] += x * sW1[jg + j][k];
    }
    #pragma unroll
    for (int j = 0; j < 8; j++) sH[r][jg + j] = fmaxf(h[j], 0.f);
    __syncthreads();
    for (int u = tid; u < 640; u += 256) {
        int row = u / 10, oo = u % 10;
        float acc = 0.f;
        #pragma unroll
        for (int j = 0; j < 32; j++) acc += sH[row][j] * sW2[oo * 32 + j];
        Pp[(size_t)(r0 + row) * 10 + oo] = acc;
    }
}

// ---------------------------------------------------------------------------
extern "C" void kernel_launch(void* const* d_in, const int* in_sizes, int n_in,
                              void* d_out, int out_size, void* d_ws, size_t ws_size,
                              hipStream_t stream)
{
    const float* img    = (const float*)d_in[0];
    const float* audio  = (const float*)d_in[1];
    const float* vis_W  = (const float*)d_in[2];
    const float* vis_b  = (const float*)d_in[3];
    const float* aud_W  = (const float*)d_in[4];
    const float* aud_b  = (const float*)d_in[5];
    const float* msv_W  = (const float*)d_in[6];
    const float* msv_b  = (const float*)d_in[7];
    const float* msa_W  = (const float*)d_in[8];
    const float* msa_b  = (const float*)d_in[9];
    const float* mmfa_W = (const float*)d_in[10];
    const float* mmfa_b = (const float*)d_in[11];
    const float* bil_W  = (const float*)d_in[12];
    const float* t_c    = (const float*)d_in[13];
    const float* out_W1 = (const float*)d_in[14];
    const float* out_b1 = (const float*)d_in[15];
    const float* out_W2 = (const float*)d_in[16];
    const float* out_b2 = (const float*)d_in[17];
    const float* clsv_W1 = (const float*)d_in[18];
    const float* clsv_W2 = (const float*)d_in[19];
    const float* clsa_W1 = (const float*)d_in[20];
    const float* clsa_W2 = (const float*)d_in[21];
    float* out = (float*)d_out;
    float* ws  = (float*)d_ws;

    constexpr size_t SD = 3072 * 256; // 786432
    // ---- scratch region S (8,388,608 floats)
    float* S = ws;
    unsigned short* visbf = (unsigned short*)(S + 2097152);
    unsigned short* audbf = (unsigned short*)(S + 4194304);
    unsigned short* msvbf = (unsigned short*)(S + 4718592);
    unsigned short* msabf = (unsigned short*)(S + 5111808);
    float* vis  = S;
    float* aud  = S + 1048576;
    float* qkv  = S;
    float* qka  = S + 1572864;
    float* al_v = S + 3145728;
    float* al_a = S + 4718592;
    float* ovb  = S;                  // end-phase
    float* oab  = S + SD;
    float* hv1  = S + 2 * SD;
    float* hv2  = S + 2 * SD + 524288;
    // ---- persistent region
    float* P = ws + 8388608;
    float* v_ms    = P;
    float* a_ms    = P + SD;
    float* x_v2    = P + 2 * SD;
    float* x_a2    = P + 3 * SD;
    float* logitsT = P + 4 * SD;                                  // [256][3072]
    unsigned short* c_va = (unsigned short*)(P + 5 * SD);         // [3072][256] bf16
    unsigned short* c_av = (unsigned short*)(P + 5 * SD + SD / 2);
    unsigned short* Wqkv = (unsigned short*)(P + 6 * SD);
    unsigned short* Wqka = Wqkv + 131072;
    unsigned short* Wcva = Wqka + 131072;
    unsigned short* Wcav = Wcva + 131072;
    float* bqkv = P + 6 * SD + 262144;
    float* bqka = bqkv + 512;
    float* bcva = bqka + 512;
    float* bcav = bcva + 256;
    unsigned short* W1bf = (unsigned short*)(bcav + 256);
    unsigned short* W2bf = W1bf + 393216;

    // ---- weight packing: 2 launches
    conv_multi<<<3552, 256, 0, stream>>>(vis_W, visbf, aud_W, audbf,
                                         msv_W, msvbf, msa_W, msabf,
                                         out_W1, W1bf, out_W2, W2bf);
    pack_mmfa<<<2049, 256, 0, stream>>>(mmfa_W, mmfa_b, Wqkv, Wqka, Wcva, Wcav,
                                        bqkv, bqka, bcva, bcav);

    // ---- encoders + multiscale
    gemm_mfma_z<1><<<dim3(16, 16, 1), 256, 0, stream>>>(
        img, img, visbf, visbf, vis_b, vis_b, vis, vis, 1024, 1024, 4096);
    gemm_mfma_z<1><<<dim3(16, 16, 1), 256, 0, stream>>>(
        audio, audio, audbf, audbf, aud_b, aud_b, aud, aud, 1024, 1024, 1024);
    gemm_mfma_z<1><<<dim3(12, 16, 2), 256, 0, stream>>>(
        vis, aud, msvbf, msabf, msv_b, msa_b, v_ms, a_ms, 1024, 768, 1024);

    const int EW_N = (int)SD;
    const int EW_G = (EW_N + 255) / 256;

    auto mmfa = [&](const float* xv, const float* xa, float* outv, float* outa) {
        gemm_mfma_z<0><<<dim3(8, 48, 2), 256, 0, stream>>>(
            xv, xa, Wqkv, Wqka, bqkv, bqka, qkv, qka, 3072, 512, 256);
        attn_packed<<<1024, 256, 0, stream>>>(qkv, qka, xv, xa, al_v, al_a);
        gemm_sigm_z<<<dim3(4, 48, 2), 256, 0, stream>>>(
            al_v, al_a, Wcva, Wcav, bcva, bcav, c_va, c_av, 3072, 256, 512);
        bilinear_col<<<dim3(256, 4), 512, 0, stream>>>(c_av, c_va, bil_W, logitsT);
        ew_mix<<<EW_G, 256, 0, stream>>>(logitsT, xv, xa, v_ms, a_ms, t_c,
                                         outv, outa, EW_N);
    };

    mmfa(v_ms, a_ms, x_v2, x_a2);   // M1 stage
    mmfa(x_v2, x_a2, ovb, oab);     // M2 stage

    float* fv = out;
    float* fa = out + 1024 * 128;
    float* pv = out + 2 * 1024 * 128;
    float* pa = pv + 1024 * 10;

    // ---- out_layer (z-fused) + fused classifiers
    gemm_mfma_z<1><<<dim3(8, 16, 2), 256, 0, stream>>>(
        ovb, oab, W1bf, W1bf, out_b1, out_b1, hv1, hv2, 1024, 512, 768);
    gemm_mfma_z<0><<<dim3(2, 16, 2), 256, 0, stream>>>(
        hv1, hv2, W2bf, W2bf, out_b2, out_b2, fv, fa, 1024, 128, 512);
    cls_fused<<<dim3(16, 2), 256, 0, stream>>>(fv, fa, clsv_W1, clsv_W2,
                                               clsa_W1, clsa_W2, pv, pa);

    (void)in_sizes; (void)n_in; (void)out_size; (void)ws_size;
}

// Round 8
// 731.166 us; speedup vs baseline: 1.1930x; 1.0686x over previous
//
#include <hip/hip_runtime.h>
#include <math.h>

// ---------------------------------------------------------------------------
// CrossModal_NN — round 8: bilinear back to grid (256,2) (r7's (256,4) re-read
// W 2x for nothing — occupancy is capped at ~2 blocks/CU either way); sRed
// double-buffer takes the cross-wave drain off the critical path (3->2
// barriers per m-step, drain overlaps staging). ew_mix_t: LDS-tile transpose
// so logitsT reads are coalesced (was stride-3072 scatter).
// ---------------------------------------------------------------------------

typedef short short8   __attribute__((ext_vector_type(8)));
typedef float floatx4  __attribute__((ext_vector_type(4)));

constexpr float NORM = 0.0625f; // 1/sqrt(256), applied AFTER softmax (faithful)

__device__ __forceinline__ unsigned short f2bf(float f) {
    union { float f; unsigned int u; } v; v.f = f;
    unsigned int r = v.u + 0x7fffu + ((v.u >> 16) & 1u); // RNE
    return (unsigned short)(r >> 16);
}
__device__ __forceinline__ float bf2f(unsigned short s) {
    union { unsigned int u; float f; } v; v.u = ((unsigned int)s) << 16;
    return v.f;
}

// ---------------- bf16 MFMA GEMM (z-fused pair): C = act(A @ W^T + bias) ----
template<int ACT>
__global__ __launch_bounds__(256)
void gemm_mfma_z(const float* __restrict__ A0, const float* __restrict__ A1,
                 const unsigned short* __restrict__ Wp0,
                 const unsigned short* __restrict__ Wp1,
                 const float* __restrict__ b0, const float* __restrict__ b1,
                 float* __restrict__ C0, float* __restrict__ C1,
                 int M, int N, int K)
{
    const float* A = blockIdx.z ? A1 : A0;
    const unsigned short* W = blockIdx.z ? Wp1 : Wp0;
    const float* bias = blockIdx.z ? b1 : b0;
    float* C = blockIdx.z ? C1 : C0;

    __shared__ short sA[64][72];
    __shared__ short sW[64][72];
    const int tid  = threadIdx.x;
    const int wave = tid >> 6, lane = tid & 63;
    const int quad = lane >> 4, l15 = lane & 15;
    const int m0 = blockIdx.y * 64, n0 = blockIdx.x * 64;
    const int mw = (wave & 1) * 32, nw = (wave >> 1) * 32;
    const int srow = tid >> 2, sseg = tid & 3;

    floatx4 P[2][2];
    #pragma unroll
    for (int f = 0; f < 2; f++)
        #pragma unroll
        for (int g = 0; g < 2; g++)
            P[f][g] = (floatx4){0.f, 0.f, 0.f, 0.f};

    for (int k0 = 0; k0 < K; k0 += 64) {
        const float* ap = A + (size_t)(m0 + srow) * K + k0 + sseg * 16;
        float4 a0 = *(const float4*)(ap);
        float4 a1 = *(const float4*)(ap + 4);
        float4 a2 = *(const float4*)(ap + 8);
        float4 a3 = *(const float4*)(ap + 12);
        union { unsigned short s[8]; short8 v; } p0, p1;
        p0.s[0] = f2bf(a0.x); p0.s[1] = f2bf(a0.y); p0.s[2] = f2bf(a0.z); p0.s[3] = f2bf(a0.w);
        p0.s[4] = f2bf(a1.x); p0.s[5] = f2bf(a1.y); p0.s[6] = f2bf(a1.z); p0.s[7] = f2bf(a1.w);
        p1.s[0] = f2bf(a2.x); p1.s[1] = f2bf(a2.y); p1.s[2] = f2bf(a2.z); p1.s[3] = f2bf(a2.w);
        p1.s[4] = f2bf(a3.x); p1.s[5] = f2bf(a3.y); p1.s[6] = f2bf(a3.z); p1.s[7] = f2bf(a3.w);
        *(short8*)&sA[srow][sseg * 16]     = p0.v;
        *(short8*)&sA[srow][sseg * 16 + 8] = p1.v;
        const unsigned short* wp = W + (size_t)(n0 + srow) * K + k0 + sseg * 16;
        *(short8*)&sW[srow][sseg * 16]     = *(const short8*)wp;
        *(short8*)&sW[srow][sseg * 16 + 8] = *(const short8*)(wp + 8);
        __syncthreads();
        #pragma unroll
        for (int kh = 0; kh < 2; kh++) {
            short8 af[2], wf[2];
            af[0] = *(short8*)&sA[mw + l15][kh * 32 + quad * 8];
            af[1] = *(short8*)&sA[mw + 16 + l15][kh * 32 + quad * 8];
            wf[0] = *(short8*)&sW[nw + l15][kh * 32 + quad * 8];
            wf[1] = *(short8*)&sW[nw + 16 + l15][kh * 32 + quad * 8];
            #pragma unroll
            for (int f = 0; f < 2; f++)
                #pragma unroll
                for (int g = 0; g < 2; g++)
                    P[f][g] = __builtin_amdgcn_mfma_f32_16x16x32_bf16(af[f], wf[g], P[f][g], 0, 0, 0);
        }
        __syncthreads();
    }
    #pragma unroll
    for (int f = 0; f < 2; f++)
        #pragma unroll
        for (int g = 0; g < 2; g++)
            #pragma unroll
            for (int r = 0; r < 4; r++) {
                int m = m0 + mw + 16 * f + quad * 4 + r;
                int n = n0 + nw + 16 * g + l15;
                float v = P[f][g][r] + bias[n];
                if (ACT) v = fmaxf(v, 0.f);
                C[(size_t)m * N + n] = v;
            }
}

// ---- z-fused GEMM with sigmoid(G*alpha)->bf16 epilogue ---------------------
__global__ __launch_bounds__(256)
void gemm_sigm_z(const float* __restrict__ A0, const float* __restrict__ A1,
                 const unsigned short* __restrict__ Wp0,
                 const unsigned short* __restrict__ Wp1,
                 const float* __restrict__ b0, const float* __restrict__ b1,
                 unsigned short* __restrict__ O0, unsigned short* __restrict__ O1,
                 int M, int N, int K)
{
    const float* A = blockIdx.z ? A1 : A0;           // alpha lives in A[.,256:512]
    const unsigned short* W = blockIdx.z ? Wp1 : Wp0;
    const float* bias = blockIdx.z ? b1 : b0;
    unsigned short* Cbf = blockIdx.z ? O1 : O0;

    __shared__ short sA[64][72];
    __shared__ short sW[64][72];
    const int tid  = threadIdx.x;
    const int wave = tid >> 6, lane = tid & 63;
    const int quad = lane >> 4, l15 = lane & 15;
    const int m0 = blockIdx.y * 64, n0 = blockIdx.x * 64;
    const int mw = (wave & 1) * 32, nw = (wave >> 1) * 32;
    const int srow = tid >> 2, sseg = tid & 3;

    floatx4 P[2][2];
    #pragma unroll
    for (int f = 0; f < 2; f++)
        #pragma unroll
        for (int g = 0; g < 2; g++)
            P[f][g] = (floatx4){0.f, 0.f, 0.f, 0.f};

    for (int k0 = 0; k0 < K; k0 += 64) {
        const float* ap = A + (size_t)(m0 + srow) * K + k0 + sseg * 16;
        float4 a0 = *(const float4*)(ap);
        float4 a1 = *(const float4*)(ap + 4);
        float4 a2 = *(const float4*)(ap + 8);
        float4 a3 = *(const float4*)(ap + 12);
        union { unsigned short s[8]; short8 v; } p0, p1;
        p0.s[0] = f2bf(a0.x); p0.s[1] = f2bf(a0.y); p0.s[2] = f2bf(a0.z); p0.s[3] = f2bf(a0.w);
        p0.s[4] = f2bf(a1.x); p0.s[5] = f2bf(a1.y); p0.s[6] = f2bf(a1.z); p0.s[7] = f2bf(a1.w);
        p1.s[0] = f2bf(a2.x); p1.s[1] = f2bf(a2.y); p1.s[2] = f2bf(a2.z); p1.s[3] = f2bf(a2.w);
        p1.s[4] = f2bf(a3.x); p1.s[5] = f2bf(a3.y); p1.s[6] = f2bf(a3.z); p1.s[7] = f2bf(a3.w);
        *(short8*)&sA[srow][sseg * 16]     = p0.v;
        *(short8*)&sA[srow][sseg * 16 + 8] = p1.v;
        const unsigned short* wp = W + (size_t)(n0 + srow) * K + k0 + sseg * 16;
        *(short8*)&sW[srow][sseg * 16]     = *(const short8*)wp;
        *(short8*)&sW[srow][sseg * 16 + 8] = *(const short8*)(wp + 8);
        __syncthreads();
        #pragma unroll
        for (int kh = 0; kh < 2; kh++) {
            short8 af[2], wf[2];
            af[0] = *(short8*)&sA[mw + l15][kh * 32 + quad * 8];
            af[1] = *(short8*)&sA[mw + 16 + l15][kh * 32 + quad * 8];
            wf[0] = *(short8*)&sW[nw + l15][kh * 32 + quad * 8];
            wf[1] = *(short8*)&sW[nw + 16 + l15][kh * 32 + quad * 8];
            #pragma unroll
            for (int f = 0; f < 2; f++)
                #pragma unroll
                for (int g = 0; g < 2; g++)
                    P[f][g] = __builtin_amdgcn_mfma_f32_16x16x32_bf16(af[f], wf[g], P[f][g], 0, 0, 0);
        }
        __syncthreads();
    }
    #pragma unroll
    for (int f = 0; f < 2; f++)
        #pragma unroll
        for (int g = 0; g < 2; g++)
            #pragma unroll
            for (int r = 0; r < 4; r++) {
                int m = m0 + mw + 16 * f + quad * 4 + r;
                int n = n0 + nw + 16 * g + l15;
                float v = P[f][g][r] + bias[n];
                float a = A[(size_t)m * 512 + 256 + n];
                Cbf[(size_t)m * N + n] = f2bf(1.f / (1.f + expf(-v * a)));
            }
}

// ---------------- fused weight converts (one launch) ------------------------
__global__ __launch_bounds__(256)
void conv_multi(const float* __restrict__ s0, unsigned short* __restrict__ d0, // vis 4194304
                const float* __restrict__ s1, unsigned short* __restrict__ d1, // aud 1048576
                const float* __restrict__ s2, unsigned short* __restrict__ d2, // msv 786432
                const float* __restrict__ s3, unsigned short* __restrict__ d3, // msa 786432
                const float* __restrict__ s4, unsigned short* __restrict__ d4, // W1  393216
                const float* __restrict__ s5, unsigned short* __restrict__ d5) // W2  65536
{
    long long g = ((long long)blockIdx.x * 256 + threadIdx.x) * 8;
    const float* src; unsigned short* dst; long long off = g;
    if      (off < 4194304)                 { src = s0; dst = d0; }
    else if ((off = g - 4194304) < 1048576) { src = s1; dst = d1; }
    else if ((off = g - 5242880) < 786432)  { src = s2; dst = d2; }
    else if ((off = g - 6029312) < 786432)  { src = s3; dst = d3; }
    else if ((off = g - 6815744) < 393216)  { src = s4; dst = d4; }
    else if ((off = g - 7208960) < 65536)   { src = s5; dst = d5; }
    else return;
    float4 a = *(const float4*)(src + off);
    float4 b = *(const float4*)(src + off + 4);
    union { unsigned short s[8]; uint4 v; } o;
    o.s[0] = f2bf(a.x); o.s[1] = f2bf(a.y); o.s[2] = f2bf(a.z); o.s[3] = f2bf(a.w);
    o.s[4] = f2bf(b.x); o.s[5] = f2bf(b.y); o.s[6] = f2bf(b.z); o.s[7] = f2bf(b.w);
    *(uint4*)(dst + off) = o.v;
}

// ---------------- mmfa weight + bias pack (one launch) ----------------------
__global__ __launch_bounds__(256)
void pack_mmfa(const float* __restrict__ mW, const float* __restrict__ mb,
               unsigned short* __restrict__ Wqkv, unsigned short* __restrict__ Wqka,
               unsigned short* __restrict__ Wcva, unsigned short* __restrict__ Wcav,
               float* __restrict__ bqkv, float* __restrict__ bqka,
               float* __restrict__ bcva, float* __restrict__ bcav)
{
    int b = blockIdx.x;
    if (b < 2048) {
        int i = b * 256 + threadIdx.x;      // over 8*65536 elements
        int w = i >> 16, r = i & 65535;
        unsigned short s = f2bf(mW[i]);
        int row = r >> 8, col = r & 255;
        switch (w) {
            case 0: Wqkv[r] = s; break;
            case 1: Wqka[r] = s; break;
            case 2: Wqkv[65536 + r] = s; break;
            case 3: Wqka[65536 + r] = s; break;
            case 4: Wcva[row * 512 + col] = s; break;
            case 5: Wcva[row * 512 + 256 + col] = s; break;
            case 6: Wcav[row * 512 + col] = s; break;
            case 7: Wcav[row * 512 + 256 + col] = s; break;
        }
    } else {
        int i = threadIdx.x;
        for (int t = i; t < 512; t += 256) {
            int c = t & 255;
            bqkv[t] = mb[(t < 256 ? 0 : 512) + c];
            bqka[t] = mb[(t < 256 ? 256 : 768) + c];
        }
        bcva[i] = mb[1024 + i] + mb[1280 + i];
        bcav[i] = mb[1536 + i] + mb[1792 + i];
    }
}

// ---------------- bilinear: column-per-block, sRed-dbuf pipeline ------------
// grid (o=256, mh=2), 512 thr / 8 waves; wave owns i in [w*32, w*32+32).
// W_o frags in VGPRs (Wr[2][8] = 64 VGPR), cav tile via LDS. 24 m-steps.
// 2 barriers/m-step; drain of step ms-1 overlaps staging of step ms.
__global__ __launch_bounds__(512, 4)
void bilinear_col(const unsigned short* __restrict__ cav, // [3072][256] bf16
                  const unsigned short* __restrict__ cva, // [3072][256] bf16
                  const float* __restrict__ Wf,           // [256][256][256] f32
                  float* __restrict__ outT)               // [256][3072] f32
{
    __shared__ short sA[64][264];
    __shared__ float sRed[2][8][64];
    const int tid  = threadIdx.x;
    const int wave = tid >> 6, lane = tid & 63;
    const int quad = lane >> 4, l15 = lane & 15;
    const int o     = blockIdx.x;
    const int mbase = blockIdx.y * 1536;
    const int i0    = wave * 32;

    // ---- load W_o fragments once (fp32 -> bf16 in-register)
    short8 Wr[2][8];
    {
        const float* wo = Wf + (size_t)o * 65536;
        #pragma unroll
        for (int f = 0; f < 2; f++) {
            const float* wrow = wo + (size_t)(i0 + 16 * f + l15) * 256 + quad * 8;
            #pragma unroll
            for (int s = 0; s < 8; s++) {
                float4 lo = *(const float4*)(wrow + s * 32);
                float4 hi = *(const float4*)(wrow + s * 32 + 4);
                union { unsigned short u[8]; short8 v; } p;
                p.u[0] = f2bf(lo.x); p.u[1] = f2bf(lo.y); p.u[2] = f2bf(lo.z); p.u[3] = f2bf(lo.w);
                p.u[4] = f2bf(hi.x); p.u[5] = f2bf(hi.y); p.u[6] = f2bf(hi.z); p.u[7] = f2bf(hi.w);
                Wr[f][s] = p.v;
            }
        }
    }

    const int srow = tid >> 3, sseg = tid & 7;
    for (int ms = 0; ms < 24; ms++) {
        const int m0 = mbase + ms * 64;
        // barrier A: prev compute's sA reads + sRed[cur] writes are done
        __syncthreads();
        // stage cav tile (all threads)
        {
            const unsigned short* src = cav + (size_t)(m0 + srow) * 256 + sseg * 32;
            #pragma unroll
            for (int u = 0; u < 4; u++)
                *(short8*)&sA[srow][sseg * 32 + u * 8] = *(const short8*)(src + u * 8);
        }
        // drain previous step's reduction (overlaps staging latency)
        if (ms > 0 && tid < 64) {
            const int pb = (ms - 1) & 1;
            float acc = sRed[pb][0][tid] + sRed[pb][1][tid] + sRed[pb][2][tid]
                      + sRed[pb][3][tid] + sRed[pb][4][tid] + sRed[pb][5][tid]
                      + sRed[pb][6][tid] + sRed[pb][7][tid];
            outT[(size_t)o * 3072 + m0 - 64 + tid] = acc;
        }
        __syncthreads();   // barrier B: sA ready

        // cva scattered loads issued ahead of MFMA burst
        uint2 raws[2][4];
        #pragma unroll
        for (int g = 0; g < 4; g++)
            #pragma unroll
            for (int f = 0; f < 2; f++)
                raws[f][g] = *(const uint2*)(cva + (size_t)(m0 + 16 * g + l15) * 256
                                                  + i0 + 16 * f + 4 * quad);

        floatx4 P2[2][4];
        #pragma unroll
        for (int f = 0; f < 2; f++)
            #pragma unroll
            for (int g = 0; g < 4; g++)
                P2[f][g] = (floatx4){0.f, 0.f, 0.f, 0.f};

        #pragma unroll
        for (int s = 0; s < 8; s++) {
            short8 bg[4];
            #pragma unroll
            for (int g = 0; g < 4; g++)
                bg[g] = *(const short8*)&sA[16 * g + l15][s * 32 + quad * 8];
            #pragma unroll
            for (int f = 0; f < 2; f++)
                #pragma unroll
                for (int g = 0; g < 4; g++)
                    P2[f][g] = __builtin_amdgcn_mfma_f32_16x16x32_bf16(Wr[f][s], bg[g], P2[f][g], 0, 0, 0);
        }

        float T[4] = {0.f, 0.f, 0.f, 0.f};
        #pragma unroll
        for (int g = 0; g < 4; g++)
            #pragma unroll
            for (int f = 0; f < 2; f++) {
                uint2 raw = raws[f][g];
                T[g] += bf2f((unsigned short)(raw.x & 0xffff)) * P2[f][g][0]
                      + bf2f((unsigned short)(raw.x >> 16))    * P2[f][g][1]
                      + bf2f((unsigned short)(raw.y & 0xffff)) * P2[f][g][2]
                      + bf2f((unsigned short)(raw.y >> 16))    * P2[f][g][3];
            }
        #pragma unroll
        for (int g = 0; g < 4; g++) {
            T[g] += __shfl_xor(T[g], 16);
            T[g] += __shfl_xor(T[g], 32);
        }
        if (quad == 0) {
            #pragma unroll
            for (int g = 0; g < 4; g++)
                sRed[ms & 1][wave][16 * g + l15] = T[g];
        }
    }
    // final drain
    __syncthreads();
    if (tid < 64) {
        float acc = sRed[1][0][tid] + sRed[1][1][tid] + sRed[1][2][tid]
                  + sRed[1][3][tid] + sRed[1][4][tid] + sRed[1][5][tid]
                  + sRed[1][6][tid] + sRed[1][7][tid];
        outT[(size_t)o * 3072 + mbase + 23 * 64 + tid] = acc;
    }
}

// ---------------- attention (packed q/k [3072][512], packed alpha out) ------
__global__ __launch_bounds__(256)
void attn_packed(const float* __restrict__ qkv, const float* __restrict__ qka,
                 const float* __restrict__ xv, const float* __restrict__ xa,
                 float* __restrict__ al_v, float* __restrict__ al_a)
{
    const int b    = blockIdx.x;
    const int tid  = threadIdx.x;
    const int wave = tid >> 6;
    const int lane = tid & 63;
    __shared__ float att[4][3][3];
    const size_t b512 = (size_t)b * 1536;
    const size_t b768 = (size_t)b * 768;
    const float* Qs[4] = {qkv, qkv, qka, qka};
    const float* Ks[4] = {qka + 256, qkv + 256, qkv + 256, qka + 256};
    const float* Xs[4] = {xa, xv, xv, xa};
    float*       Os[4] = {al_v, al_v + 256, al_a, al_a + 256};
    const float* q = Qs[wave] + b512;
    const float* k = Ks[wave] + b512;
    float part[9] = {};
    for (int d = lane; d < 256; d += 64) {
        float q0 = q[d], q1 = q[512 + d], q2 = q[1024 + d];
        float k0 = k[d], k1 = k[512 + d], k2 = k[1024 + d];
        part[0] += q0 * k0; part[1] += q0 * k1; part[2] += q0 * k2;
        part[3] += q1 * k0; part[4] += q1 * k1; part[5] += q1 * k2;
        part[6] += q2 * k0; part[7] += q2 * k1; part[8] += q2 * k2;
    }
    #pragma unroll
    for (int off = 32; off > 0; off >>= 1)
        #pragma unroll
        for (int i = 0; i < 9; i++) part[i] += __shfl_down(part[i], off);
    if (lane == 0) {
        #pragma unroll
        for (int s = 0; s < 3; s++) {
            float a0 = part[s * 3], a1 = part[s * 3 + 1], a2 = part[s * 3 + 2];
            float mx = fmaxf(a0, fmaxf(a1, a2));
            float e0 = expf(a0 - mx), e1 = expf(a1 - mx), e2 = expf(a2 - mx);
            float inv = NORM / (e0 + e1 + e2);
            att[wave][s][0] = e0 * inv;
            att[wave][s][1] = e1 * inv;
            att[wave][s][2] = e2 * inv;
        }
    }
    __syncthreads();
    const int d = tid;
    #pragma unroll
    for (int w = 0; w < 4; w++) {
        const float* x = Xs[w] + b768;
        float x0 = x[d], x1 = x[256 + d], x2 = x[512 + d];
        float* o = Os[w] + b512;
        #pragma unroll
        for (int s = 0; s < 3; s++)
            o[s * 512 + d] = att[w][s][0] * x0 + att[w][s][1] * x1 + att[w][s][2] * x2;
    }
}

// ---------------- elementwise mix, transposed-tile version ------------------
// grid (48 m-tiles, 4 o-tiles), 256 thr. LDS transpose of logitsT so both
// the logitsT read and the x/b/out accesses are coalesced.
__global__ __launch_bounds__(256)
void ew_mix_t(const float* __restrict__ logitsT, const float* __restrict__ xv,
              const float* __restrict__ xa, const float* __restrict__ bv,
              const float* __restrict__ ba, const float* __restrict__ tc,
              float* __restrict__ outv, float* __restrict__ outa)
{
    __shared__ float sL[64][65];
    const int tid = threadIdx.x;
    const int m0 = blockIdx.x * 64, o0 = blockIdx.y * 64;
    // load logitsT tile [64 o][64 m], coalesced over m
    {
        int r = tid >> 2, cs = (tid & 3) * 16;   // o-row r, m-seg cs
        const float* src = logitsT + (size_t)(o0 + r) * 3072 + m0 + cs;
        #pragma unroll
        for (int u = 0; u < 4; u++)
            *(float4*)&sL[r][cs + u * 4] = *(const float4*)(src + u * 4);
    }
    __syncthreads();
    const float tcv = tc[0];
    int mr = tid >> 2, os = (tid & 3) * 16;      // m-row mr, o-seg os
    size_t base = (size_t)(m0 + mr) * 256 + o0 + os;
    #pragma unroll
    for (int u = 0; u < 4; u++) {
        float4 xvv = *(const float4*)(xv + base + u * 4);
        float4 xav = *(const float4*)(xa + base + u * 4);
        float4 bvv = *(const float4*)(bv + base + u * 4);
        float4 bav = *(const float4*)(ba + base + u * 4);
        float4 ov, oa;
        float* pxv = (float*)&xvv; float* pxa = (float*)&xav;
        float* pbv = (float*)&bvv; float* pba = (float*)&bav;
        float* pov = (float*)&ov;  float* poa = (float*)&oa;
        #pragma unroll
        for (int e = 0; e < 4; e++) {
            float j = 1.f / (1.f + expf(-sL[os + u * 4 + e][mr]));
            float M = tcv * j * pxv[e] + (1.f - j) * pxa[e];
            pov[e] = M * pbv[e];
            poa[e] = M * pba[e];
        }
        *(float4*)(outv + base + u * 4) = ov;
        *(float4*)(outa + base + u * 4) = oa;
    }
}

// ---------------- fused classifier: p = relu(f @ W1^T) @ W2^T ---------------
__global__ __launch_bounds__(256)
void cls_fused(const float* __restrict__ fv, const float* __restrict__ fa,
               const float* __restrict__ Wv1, const float* __restrict__ Wv2,
               const float* __restrict__ Wa1, const float* __restrict__ Wa2,
               float* __restrict__ pv, float* __restrict__ pa)
{
    const int z = blockIdx.y;
    const float* F  = z ? fa  : fv;
    const float* W1 = z ? Wa1 : Wv1;   // [32][128]
    const float* W2 = z ? Wa2 : Wv2;   // [10][32]
    float* Pp       = z ? pa  : pv;
    __shared__ float sX[64][132];
    __shared__ float sW1[32][133];
    __shared__ float sH[64][33];
    __shared__ float sW2[320];
    const int tid = threadIdx.x;
    const int r0  = blockIdx.x * 64;
    for (int u = tid; u < 64 * 32; u += 256) {
        int row = u >> 5, seg = u & 31;
        *(float4*)&sX[row][seg * 4] = *(const float4*)(F + (size_t)(r0 + row) * 128 + seg * 4);
    }
    for (int u = tid; u < 32 * 128; u += 256) {
        int row = u >> 7, k = u & 127;
        sW1[row][k] = W1[row * 128 + k];
    }
    if (tid < 80) ((float4*)sW2)[tid] = ((const float4*)W2)[tid];
    __syncthreads();
    const int r = tid >> 2, jg = (tid & 3) * 8;
    float h[8] = {};
    for (int k = 0; k < 128; k++) {
        float x = sX[r][k];
        #pragma unroll
        for (int j = 0; j < 8; j++) h[j] += x * sW1[jg + j][k];
    }
    #pragma unroll
    for (int j = 0; j < 8; j++) sH[r][jg + j] = fmaxf(h[j], 0.f);
    __syncthreads();
    for (int u = tid; u < 640; u += 256) {
        int row = u / 10, oo = u % 10;
        float acc = 0.f;
        #pragma unroll
        for (int j = 0; j < 32; j++) acc += sH[row][j] * sW2[oo * 32 + j];
        Pp[(size_t)(r0 + row) * 10 + oo] = acc;
    }
}

// ---------------------------------------------------------------------------
extern "C" void kernel_launch(void* const* d_in, const int* in_sizes, int n_in,
                              void* d_out, int out_size, void* d_ws, size_t ws_size,
                              hipStream_t stream)
{
    const float* img    = (const float*)d_in[0];
    const float* audio  = (const float*)d_in[1];
    const float* vis_W  = (const float*)d_in[2];
    const float* vis_b  = (const float*)d_in[3];
    const float* aud_W  = (const float*)d_in[4];
    const float* aud_b  = (const float*)d_in[5];
    const float* msv_W  = (const float*)d_in[6];
    const float* msv_b  = (const float*)d_in[7];
    const float* msa_W  = (const float*)d_in[8];
    const float* msa_b  = (const float*)d_in[9];
    const float* mmfa_W = (const float*)d_in[10];
    const float* mmfa_b = (const float*)d_in[11];
    const float* bil_W  = (const float*)d_in[12];
    const float* t_c    = (const float*)d_in[13];
    const float* out_W1 = (const float*)d_in[14];
    const float* out_b1 = (const float*)d_in[15];
    const float* out_W2 = (const float*)d_in[16];
    const float* out_b2 = (const float*)d_in[17];
    const float* clsv_W1 = (const float*)d_in[18];
    const float* clsv_W2 = (const float*)d_in[19];
    const float* clsa_W1 = (const float*)d_in[20];
    const float* clsa_W2 = (const float*)d_in[21];
    float* out = (float*)d_out;
    float* ws  = (float*)d_ws;

    constexpr size_t SD = 3072 * 256; // 786432
    // ---- scratch region S (8,388,608 floats)
    float* S = ws;
    unsigned short* visbf = (unsigned short*)(S + 2097152);
    unsigned short* audbf = (unsigned short*)(S + 4194304);
    unsigned short* msvbf = (unsigned short*)(S + 4718592);
    unsigned short* msabf = (unsigned short*)(S + 5111808);
    float* vis  = S;
    float* aud  = S + 1048576;
    float* qkv  = S;
    float* qka  = S + 1572864;
    float* al_v = S + 3145728;
    float* al_a = S + 4718592;
    float* ovb  = S;                  // end-phase
    float* oab  = S + SD;
    float* hv1  = S + 2 * SD;
    float* hv2  = S + 2 * SD + 524288;
    // ---- persistent region
    float* P = ws + 8388608;
    float* v_ms    = P;
    float* a_ms    = P + SD;
    float* x_v2    = P + 2 * SD;
    float* x_a2    = P + 3 * SD;
    float* logitsT = P + 4 * SD;                                  // [256][3072]
    unsigned short* c_va = (unsigned short*)(P + 5 * SD);         // [3072][256] bf16
    unsigned short* c_av = (unsigned short*)(P + 5 * SD + SD / 2);
    unsigned short* Wqkv = (unsigned short*)(P + 6 * SD);
    unsigned short* Wqka = Wqkv + 131072;
    unsigned short* Wcva = Wqka + 131072;
    unsigned short* Wcav = Wcva + 131072;
    float* bqkv = P + 6 * SD + 262144;
    float* bqka = bqkv + 512;
    float* bcva = bqka + 512;
    float* bcav = bcva + 256;
    unsigned short* W1bf = (unsigned short*)(bcav + 256);
    unsigned short* W2bf = W1bf + 393216;

    // ---- weight packing: 2 launches
    conv_multi<<<3552, 256, 0, stream>>>(vis_W, visbf, aud_W, audbf,
                                         msv_W, msvbf, msa_W, msabf,
                                         out_W1, W1bf, out_W2, W2bf);
    pack_mmfa<<<2049, 256, 0, stream>>>(mmfa_W, mmfa_b, Wqkv, Wqka, Wcva, Wcav,
                                        bqkv, bqka, bcva, bcav);

    // ---- encoders + multiscale
    gemm_mfma_z<1><<<dim3(16, 16, 1), 256, 0, stream>>>(
        img, img, visbf, visbf, vis_b, vis_b, vis, vis, 1024, 1024, 4096);
    gemm_mfma_z<1><<<dim3(16, 16, 1), 256, 0, stream>>>(
        audio, audio, audbf, audbf, aud_b, aud_b, aud, aud, 1024, 1024, 1024);
    gemm_mfma_z<1><<<dim3(12, 16, 2), 256, 0, stream>>>(
        vis, aud, msvbf, msabf, msv_b, msa_b, v_ms, a_ms, 1024, 768, 1024);

    auto mmfa = [&](const float* xv, const float* xa, float* outv, float* outa) {
        gemm_mfma_z<0><<<dim3(8, 48, 2), 256, 0, stream>>>(
            xv, xa, Wqkv, Wqka, bqkv, bqka, qkv, qka, 3072, 512, 256);
        attn_packed<<<1024, 256, 0, stream>>>(qkv, qka, xv, xa, al_v, al_a);
        gemm_sigm_z<<<dim3(4, 48, 2), 256, 0, stream>>>(
            al_v, al_a, Wcva, Wcav, bcva, bcav, c_va, c_av, 3072, 256, 512);
        bilinear_col<<<dim3(256, 2), 512, 0, stream>>>(c_av, c_va, bil_W, logitsT);
        ew_mix_t<<<dim3(48, 4), 256, 0, stream>>>(logitsT, xv, xa, v_ms, a_ms,
                                                  t_c, outv, outa);
    };

    mmfa(v_ms, a_ms, x_v2, x_a2);   // M1 stage
    mmfa(x_v2, x_a2, ovb, oab);     // M2 stage

    float* fv = out;
    float* fa = out + 1024 * 128;
    float* pv = out + 2 * 1024 * 128;
    float* pa = pv + 1024 * 10;

    // ---- out_layer (z-fused) + fused classifiers
    gemm_mfma_z<1><<<dim3(8, 16, 2), 256, 0, stream>>>(
        ovb, oab, W1bf, W1bf, out_b1, out_b1, hv1, hv2, 1024, 512, 768);
    gemm_mfma_z<0><<<dim3(2, 16, 2), 256, 0, stream>>>(
        hv1, hv2, W2bf, W2bf, out_b2, out_b2, fv, fa, 1024, 128, 512);
    cls_fused<<<dim3(16, 2), 256, 0, stream>>>(fv, fa, clsv_W1, clsv_W2,
                                               clsa_W1, clsa_W2, pv, pa);

    (void)in_sizes; (void)n_in; (void)out_size; (void)ws_size;
}